// Round 1
// baseline (274.624 us; speedup 1.0000x reference)
//
#include <hip/hip_runtime.h>
#include <cstdint>
#include <cstddef>

typedef __bf16 bf16x8 __attribute__((ext_vector_type(8)));
typedef __bf16 bf16x4 __attribute__((ext_vector_type(4)));
typedef short s16x4 __attribute__((ext_vector_type(4)));
typedef float f32x4 __attribute__((ext_vector_type(4)));

__device__ __forceinline__ ushort f2bf(float f) {
  union { float f; uint32_t u; } v; v.f = f;
  uint32_t r = (v.u + 0x7fffu + ((v.u >> 16) & 1u)) >> 16;
  return (ushort)r;
}

__device__ __forceinline__ float fast_exp2(float x) {
#if defined(__HIP_DEVICE_COMPILE__) && __has_builtin(__builtin_amdgcn_exp2f)
  return __builtin_amdgcn_exp2f(x);
#else
  return exp2f(x);
#endif
}

// K=16 bf16 MFMA (C-layout of a 16x16 result feeds directly as B operand).
__device__ __forceinline__ f32x4 mfma16(bf16x4 a, bf16x4 b, f32x4 c) {
#if defined(__HIP_DEVICE_COMPILE__)
#if __has_builtin(__builtin_amdgcn_mfma_f32_16x16x16_bf16)
  return __builtin_amdgcn_mfma_f32_16x16x16_bf16(a, b, c, 0, 0, 0);
#else
  return __builtin_amdgcn_mfma_f32_16x16x16bf16_1k(
      __builtin_bit_cast(s16x4, a), __builtin_bit_cast(s16x4, b), c, 0, 0, 0);
#endif
#else
  (void)a; (void)b;
  return c;  // host stub, never executed
#endif
}

__device__ __forceinline__ void glds16(const ushort* g, ushort* l) {
  __builtin_amdgcn_global_load_lds((const __attribute__((address_space(1))) void*)g,
                                   (__attribute__((address_space(3))) void*)l, 16, 0, 0);
}

// ---------------- fp32 -> bf16 convert (vectorized) ----------------
__global__ void conv_bf16(const float4* __restrict__ in, ushort4* __restrict__ out, int n4) {
  int i = blockIdx.x * blockDim.x + threadIdx.x;
  if (i < n4) {
    float4 v = in[i];
    ushort4 o;
    o.x = f2bf(v.x); o.y = f2bf(v.y); o.z = f2bf(v.z); o.w = f2bf(v.w);
    out[i] = o;
  }
}

// ---------------- fp32 [R][C] -> bf16 [C][R] transpose ----------------
__global__ void transpose_f32_bf16(const float* __restrict__ in, ushort* __restrict__ out,
                                   int R, int C) {
  __shared__ ushort t[32][33];
  int c0 = blockIdx.x * 32, r0 = blockIdx.y * 32;
  int tx = threadIdx.x, ty = threadIdx.y;  // 32 x 8
#pragma unroll
  for (int i = 0; i < 4; ++i)
    t[ty + i * 8][tx] = f2bf(in[(size_t)(r0 + ty + i * 8) * C + c0 + tx]);
  __syncthreads();
#pragma unroll
  for (int i = 0; i < 4; ++i)
    out[(size_t)(c0 + ty + i * 8) * R + r0 + tx] = t[tx][ty + i * 8];
}

// =====================================================================
// 8-phase 256x256 QKV projection GEMM (T2+T3+T4+T5 per the template).
// A[8192][1024] bf16, Bt[3072][1024] bf16 (row = N, K-contiguous).
// Scatters to Q[B,H,S,64] (scaled 0.125*log2e), K[B,H,S,64],
// V^T tiled Vt[bh][s>>6][d][64].
//
// Geometry: BM=BN=256, BK=64, 8 waves (2M x 4N), 512 thr, LDS 128 KiB.
// Per-wave output 128x64 as interleaved quadrants:
//   row(m) = (m>>2)*128 + wr*64 + (m&3)*16   (qm = m>>2 selects A half)
//   col(n) = (n>>1)*128 + wc*32 + (n&1)*16   (qn = n>>1 selects B half)
// so each phase (qm,qn) touches exactly one A half + one B half -> slots
// free early, enabling the counted-vmcnt 3-half-tile-in-flight pipeline.
//
// LDS: half-tile = 128 rows x 64 bf16 (16 KiB). Chunk swizzle: 16B chunk
// p of row r holds logical chunk p ^ (r&7)  (source-side pre-swizzle,
// global_load_lds dest stays linear base+lane*16). Fragment ds_read_b128
// then lands 2-way bank-aliased = free (m136).
//
// Stage stream (1 half / phase, safety: slot restaged only after its last
// reader phase's end-barrier; per-wave vmcnt BEFORE the shared barrier
// makes all waves' DMA visible):
//   ph0: Ah1(t+1)   ph1: Ah0(t+2)   ph2: Bh0(t+2)   ph3: Bh1(t+2)
// boundary wait: vmcnt(6) (= 3 newest half-tiles in flight), vmcnt(0)
// only before the last K-tile.
// =====================================================================
#define BAR8() do { asm volatile("" ::: "memory"); \
                    __builtin_amdgcn_s_barrier();  \
                    asm volatile("" ::: "memory"); } while (0)
#define LGKM0() asm volatile("s_waitcnt lgkmcnt(0)" ::: "memory")
#define VMC6()  asm volatile("s_waitcnt vmcnt(6)" ::: "memory")
#define VMC4()  asm volatile("s_waitcnt vmcnt(4)" ::: "memory")
#define VMC0()  asm volatile("s_waitcnt vmcnt(0)" ::: "memory")

#define LOADA(b_, qm_) do {                                               \
    const ushort* _ab = smem + ((b_) * 2 + (qm_)) * 8192 + aRow;          \
    _Pragma("unroll")                                                     \
    for (int m_ = 0; m_ < 4; ++m_) {                                      \
      aF[m_][0] = *(const bf16x8*)(_ab + m_ * 1024 + cK0);                \
      aF[m_][1] = *(const bf16x8*)(_ab + m_ * 1024 + cK1);                \
    }                                                                     \
  } while (0)

#define LOADB(b_, qn_) do {                                               \
    const ushort* _bb = smem + 32768 + ((b_) * 2 + (qn_)) * 8192 + bRow;  \
    _Pragma("unroll")                                                     \
    for (int n_ = 0; n_ < 2; ++n_) {                                      \
      bF[qn_][n_][0] = *(const bf16x8*)(_bb + n_ * 1024 + cK0);           \
      bF[qn_][n_][1] = *(const bf16x8*)(_bb + n_ * 1024 + cK1);           \
    }                                                                     \
  } while (0)

#define MMAC(qm_, qn_) do {                                               \
    __builtin_amdgcn_s_setprio(1);                                        \
    _Pragma("unroll")                                                     \
    for (int m_ = 0; m_ < 4; ++m_)                                        \
      _Pragma("unroll")                                                   \
      for (int n_ = 0; n_ < 2; ++n_) {                                    \
        acc[(qm_) * 4 + m_][(qn_) * 2 + n_] =                             \
            __builtin_amdgcn_mfma_f32_16x16x32_bf16(                      \
                aF[m_][0], bF[qn_][n_][0],                                \
                acc[(qm_) * 4 + m_][(qn_) * 2 + n_], 0, 0, 0);            \
        acc[(qm_) * 4 + m_][(qn_) * 2 + n_] =                             \
            __builtin_amdgcn_mfma_f32_16x16x32_bf16(                      \
                aF[m_][1], bF[qn_][n_][1],                                \
                acc[(qm_) * 4 + m_][(qn_) * 2 + n_], 0, 0, 0);            \
      }                                                                   \
    __builtin_amdgcn_s_setprio(0);                                        \
  } while (0)

__launch_bounds__(512, 2)
__global__ void gemm8_qkv(const ushort* __restrict__ A, const ushort* __restrict__ Bt,
                          const float* __restrict__ bias,
                          ushort* __restrict__ o0, ushort* __restrict__ o1,
                          ushort* __restrict__ o2) {
  constexpr int K = 1024;
  constexpr int NT = 16;  // K / 64
  __shared__ ushort smem[65536];  // 128 KiB: A halves [0,32768), B halves [32768,65536)

  const int tid = threadIdx.x;
  const int wid = tid >> 6;
  const int lane = tid & 63;
  const int quad = lane >> 4;
  const int l16 = lane & 15;
  const int wr = wid >> 2;   // 0..1
  const int wc = wid & 3;    // 0..3

  // XCD-aware bijective swizzle: 384 blocks = 8 XCDs x 48 contiguous
  int wg = blockIdx.y * gridDim.x + blockIdx.x;
  const int nwgx = gridDim.x;                    // 12
  const int cpx = (nwgx * gridDim.y) >> 3;       // 48
  wg = (wg & 7) * cpx + (wg >> 3);
  const int m0 = (wg / nwgx) * 256;
  const int n0 = (wg % nwgx) * 256;

  // ---- staging addressing: 2 x glds16 per half-tile per thread ----
  const int r0 = tid >> 3;                      // row 0..63 (l=0), +64 (l=1)
  const int cch = (tid & 7) ^ (r0 & 7);         // pre-swizzled logical chunk
  const ushort* gA = A + (size_t)(m0 + r0) * K + cch * 8;
  const ushort* gB = Bt + (size_t)(n0 + r0) * K + cch * 8;
  ushort* lA = smem + tid * 8;
  ushort* lB = smem + 32768 + tid * 8;

  auto stageA = [&](int t, int h, int b) {
    const ushort* s = gA + (h * 128) * K + t * 64;
    ushort* d = lA + (b * 2 + h) * 8192;
    glds16(s, d);
    glds16(s + 64 * K, d + 4096);
  };
  auto stageB = [&](int t, int h, int b) {
    const ushort* s = gB + (h * 128) * K + t * 64;
    ushort* d = lB + (b * 2 + h) * 8192;
    glds16(s, d);
    glds16(s + 64 * K, d + 4096);
  };

  // ---- fragment read addressing (2-way aliased after swizzle = free) ----
  const int rkey = l16 & 7;
  const int aRow = (wr * 64 + l16) * 64;
  const int bRow = (wc * 32 + l16) * 64;
  const int cK0 = (quad ^ rkey) * 8;        // kk=0: logical chunk quad
  const int cK1 = ((quad + 4) ^ rkey) * 8;  // kk=1: logical chunk 4+quad

  f32x4 acc[8][4];
#pragma unroll
  for (int i = 0; i < 8; ++i)
#pragma unroll
    for (int j = 0; j < 4; ++j) acc[i][j] = (f32x4){0.f, 0.f, 0.f, 0.f};
  bf16x8 aF[4][2], bF[2][2][2];

  // ---- prologue: tile0 (4 halves) + tile1 {Ah0,Bh0,Bh1} ----
  stageA(0, 0, 0); stageB(0, 0, 0); stageA(0, 1, 0); stageB(0, 1, 0);
  VMC4();
  stageA(1, 0, 1); stageB(1, 0, 1); stageB(1, 1, 1);
  VMC6();
  BAR8();

#pragma unroll 2
  for (int t = 0; t < NT; ++t) {
    const int b = t & 1;
    // phase 0: quadrant (0,0) -- reads Ah0(b), Bh0(b)
    LOADA(b, 0);
    LOADB(b, 0);
    if (t + 1 < NT) stageA(t + 1, 1, b ^ 1);   // Ah1(t+1): slot free since t-1 ph2
    BAR8();
    LGKM0();
    MMAC(0, 0);
    BAR8();
    // phase 1: quadrant (0,1) -- reads Bh1(b); Ah0(b) now free
    LOADB(b, 1);
    if (t + 2 < NT) stageA(t + 2, 0, b);
    BAR8();
    LGKM0();
    MMAC(0, 1);
    BAR8();
    // phase 2: quadrant (1,0) -- reads Ah1(b); Bh0(b) now free
    LOADA(b, 1);
    if (t + 2 < NT) stageB(t + 2, 0, b);
    BAR8();
    LGKM0();
    MMAC(1, 0);
    BAR8();
    // phase 3: quadrant (1,1) -- register-only; Bh1(b) now free
    if (t + 2 < NT) stageB(t + 2, 1, b);
    BAR8();
    LGKM0();
    MMAC(1, 1);
    // counted boundary wait BEFORE the barrier (per-wave vmcnt + barrier
    // => all waves' staged halves visible). Never 0 in steady state.
    if (t == NT - 2) { VMC0(); } else if (t < NT - 2) { VMC6(); }
    BAR8();
  }

  // ---- epilogue: reuse the 128 KiB LDS as the full 256x256 bf16 tile ----
  // element (R,C) at R*256 + ((C>>3)^(R&7))*8 + (C&7)  (granule swizzle;
  // V stored transposed: roles of R and C swapped).
  const int colr = n0 & 1023;
  const int sel = n0 >> 10;          // 0=Q 1=K 2=V (256-col tile never straddles)
  const int hbase = colr >> 6;
  const int bb = m0 >> 11;
  const int s0 = m0 & 2047;

#pragma unroll
  for (int m = 0; m < 8; ++m) {
    const int Rl = (m >> 2) * 128 + wr * 64 + (m & 3) * 16 + quad * 4;
#pragma unroll
    for (int n = 0; n < 4; ++n) {
      const int C = (n >> 1) * 128 + wc * 32 + (n & 1) * 16 + l16;
      const float bv = bias[n0 + C];
#pragma unroll
      for (int r = 0; r < 4; ++r) {
        float v = acc[m][n][r] + bv;
        if (sel == 0) v *= 0.18033688011112042f;  // (1/8)*log2(e)
        const ushort u = f2bf(v);
        const int R = Rl + r;
        if (sel == 2)
          smem[(C << 8) + ((((R >> 3) ^ (C & 7)) << 3) | (R & 7))] = u;
        else
          smem[(R << 8) + ((((C >> 3) ^ (R & 7)) << 3) | (C & 7))] = u;
      }
    }
  }
  __syncthreads();

  // 1024 chunks of 128B, 2 per thread, 128B-coalesced per wave.
  if (sel != 2) {
    ushort* o = sel ? o1 : o0;
#pragma unroll
    for (int l = 0; l < 2; ++l) {
      const int q = l * 512 + tid;
      const int hh = q >> 8;            // head within tile 0..3
      const int s_loc = q & 255;        // s-row within tile
      ushort* dst = o + ((size_t)((bb * 16 + hbase + hh) * 2048 + s0 + s_loc)) * 64;
      const int key = s_loc & 7;
      const uint4* srow = (const uint4*)(smem + (s_loc << 8));
#pragma unroll
      for (int g = 0; g < 8; ++g)
        ((uint4*)dst)[g] = srow[(hh * 8 + g) ^ key];
    }
  } else {
#pragma unroll
    for (int l = 0; l < 2; ++l) {
      const int q = l * 512 + tid;
      const int sc4 = q >> 8;           // s-chunk of 64 within tile
      const int d_loc = q & 255;        // d-row (4 heads x 64)
      ushort* dst = o2 +
          ((size_t)((bb * 16 + hbase + (d_loc >> 6)) * 32 + (s0 >> 6) + sc4) << 12) +
          (d_loc & 63) * 64;
      const int key = d_loc & 7;
      const uint4* srow = (const uint4*)(smem + (d_loc << 8));
#pragma unroll
      for (int g = 0; g < 8; ++g)
        ((uint4*)dst)[g] = srow[(sc4 * 8 + g) ^ key];
    }
  }
}

// ---------------- bf16 GEMM: C = A[M][K] @ Bt[N][K]^T + bias ----------------
// (retained for the output projection, MODE 1: fp32 out[row*N+col] direct)
template <int MODE>
__launch_bounds__(256)
__global__ void gemm_bt(const ushort* __restrict__ A, const ushort* __restrict__ Bt,
                        const float* __restrict__ bias,
                        ushort* __restrict__ o0, ushort* __restrict__ o1,
                        ushort* __restrict__ o2, float* __restrict__ of,
                        int M, int N, int K) {
  __shared__ ushort As[128 * 32];
  __shared__ ushort Bs[128 * 32];
  __shared__ ushort Ts[MODE == 0 ? 4 * 64 * 68 : 4];  // per-wave epilogue staging
  const int tid = threadIdx.x;
  const int wid = tid >> 6;
  const int lane = tid & 63;
  const int quad = lane >> 4;
  const int l16 = lane & 15;
  const int m0 = blockIdx.y * 128;
  const int n0 = blockIdx.x * 128;
  const int wm = (wid >> 1) * 64;
  const int wn = (wid & 1) * 64;
  const int srow = lane >> 2;          // 0..15
  const int scol = (lane & 3) << 3;    // 0,8,16,24

  f32x4 acc[4][4];
#pragma unroll
  for (int i = 0; i < 4; ++i)
#pragma unroll
    for (int j = 0; j < 4; ++j) acc[i][j] = (f32x4){0.f, 0.f, 0.f, 0.f};

  const int c0 = wid * 2, c1 = wid * 2 + 1;
  const ushort* gA0 = A + (size_t)(m0 + c0 * 16 + srow) * K + scol;
  const ushort* gA1 = A + (size_t)(m0 + c1 * 16 + srow) * K + scol;
  const ushort* gB0 = Bt + (size_t)(n0 + c0 * 16 + srow) * K + scol;
  const ushort* gB1 = Bt + (size_t)(n0 + c1 * 16 + srow) * K + scol;
  ushort* lA0 = As + c0 * 512 + lane * 8;
  ushort* lA1 = As + c1 * 512 + lane * 8;
  ushort* lB0 = Bs + c0 * 512 + lane * 8;
  ushort* lB1 = Bs + c1 * 512 + lane * 8;

  for (int k0 = 0; k0 < K; k0 += 32) {
    __syncthreads();
    glds16(gA0 + k0, lA0);
    glds16(gA1 + k0, lA1);
    glds16(gB0 + k0, lB0);
    glds16(gB1 + k0, lB1);
    __syncthreads();
    bf16x8 af[4], bfr[4];
#pragma unroll
    for (int i = 0; i < 4; ++i)
      af[i] = *(const bf16x8*)(As + (wm + i * 16 + l16) * 32 + quad * 8);
#pragma unroll
    for (int j = 0; j < 4; ++j)
      bfr[j] = *(const bf16x8*)(Bs + (wn + j * 16 + l16) * 32 + quad * 8);
#pragma unroll
    for (int i = 0; i < 4; ++i)
#pragma unroll
      for (int j = 0; j < 4; ++j)
        acc[i][j] = __builtin_amdgcn_mfma_f32_16x16x32_bf16(af[i], bfr[j], acc[i][j], 0, 0, 0);
  }

  if (MODE == 1) {
#pragma unroll
    for (int i = 0; i < 4; ++i)
#pragma unroll
      for (int j = 0; j < 4; ++j) {
        const int col = n0 + wn + j * 16 + l16;
        const float bv = bias[col];
#pragma unroll
        for (int r = 0; r < 4; ++r) {
          const int row = m0 + wm + i * 16 + quad * 4 + r;
          of[(size_t)row * N + col] = acc[i][j][r] + bv;
        }
      }
  } else {
    ushort* T = &Ts[wid * (64 * 68)];
    const int col0 = n0 + wn;            // block+wave uniform
    const int sel = col0 >> 10;          // 0=Q 1=K 2=V
    const int hh = (col0 & 1023) >> 6;
    const int row0 = m0 + wm;
    const int bb = row0 >> 11;
    const int s0 = row0 & 2047;
    const size_t bh = (size_t)(bb * 16 + hh);
#pragma unroll
    for (int j = 0; j < 4; ++j) {
      const float bv = bias[col0 + j * 16 + l16];
      const int dl = j * 16 + l16;
#pragma unroll
      for (int i = 0; i < 4; ++i) {
#pragma unroll
        for (int r = 0; r < 4; ++r) {
          const int sl = i * 16 + quad * 4 + r;
          float v = acc[i][j][r] + bv;
          if (sel == 0) v *= 0.18033688011112042f;
          const ushort u = f2bf(v);
          if (sel == 2) T[dl * 68 + sl] = u;
          else          T[sl * 68 + dl] = u;
        }
      }
    }
    asm volatile("s_waitcnt lgkmcnt(0)" ::: "memory");
    ushort* dst;
    if (sel == 2) dst = o2 + ((bh * 32 + (s0 >> 6)) << 12) + lane * 64;
    else          dst = (sel == 0 ? o0 : o1) + (bh * 2048 + s0 + lane) * 64;
    const ushort* Trow = &T[lane * 68];
#pragma unroll
    for (int k = 0; k < 16; ++k)
      *(ushort4*)(dst + k * 4) = *(const ushort4*)(Trow + k * 4);
  }
}

// ---------------- flash attention (causal) ----------------
__launch_bounds__(256)
__global__ void attn_fused(const ushort* __restrict__ Qb, const ushort* __restrict__ Kb,
                           const ushort* __restrict__ Vt, ushort* __restrict__ Ob) {
  const int bh = blockIdx.y;       // b*16 + h
  const int pair = blockIdx.x;     // 0..7
  const int tid = threadIdx.x;
  const int wid = tid >> 6;
  const int lane = tid & 63;
  const int quad = lane >> 4;
  const int l16 = lane & 15;

  __shared__ ushort Ks[2][2][64 * 32];
  __shared__ ushort Vs[2][2][64 * 32];

  const int lr = lane >> 2;
  const int jphys = lane & 3;
  const int skey = (lr >> 1) & 3;
  const int jlog = jphys ^ skey;
  const int srow = wid * 16 + lr;
  const ushort* KgL = Kb + (size_t)bh * 2048 * 64 + (size_t)srow * 64 + jlog * 8;
  const ushort* VgL = Vt + (size_t)bh * 32 * 4096 + (size_t)srow * 64 + jlog * 8;
  ushort* ldsK0[2], *ldsK1[2], *ldsV0[2], *ldsV1[2];
#pragma unroll
  for (int buf = 0; buf < 2; ++buf) {
    ldsK0[buf] = &Ks[buf][0][wid * 16 * 32] + lane * 8;
    ldsK1[buf] = &Ks[buf][1][wid * 16 * 32] + lane * 8;
    ldsV0[buf] = &Vs[buf][0][wid * 16 * 32] + lane * 8;
    ldsV1[buf] = &Vs[buf][1][wid * 16 * 32] + lane * 8;
  }
  auto stage = [&](int jt) {
    const int buf = jt & 1;
    const ushort* ks = KgL + (size_t)jt * 4096;
    const ushort* vs = VgL + (size_t)jt * 4096;
    glds16(ks, ldsK0[buf]);
    glds16(ks + 32, ldsK1[buf]);
    glds16(vs, ldsV0[buf]);
    glds16(vs + 32, ldsV1[buf]);
  };

  const int rkey = (l16 >> 1) & 3;
  const int b = bh >> 4, h = bh & 15;

  auto process = [&](int qt) {
    const int qg0 = qt * 128 + wid * 32;

    const ushort* Qg = Qb + ((size_t)bh * 2048 + qg0) * 64;
    bf16x8 qa[2][2];
#pragma unroll
    for (int f = 0; f < 2; ++f)
#pragma unroll
      for (int hh = 0; hh < 2; ++hh)
        qa[f][hh] = *(const bf16x8*)(Qg + (f * 16 + l16) * 64 + hh * 32 + quad * 8);

    f32x4 o[2][4];
    float rs[2];
#pragma unroll
    for (int f = 0; f < 2; ++f) {
      rs[f] = 0.f;
#pragma unroll
      for (int m = 0; m < 4; ++m) o[f][m] = (f32x4){0.f, 0.f, 0.f, 0.f};
    }

    const int nIt = 2 * qt + 2;
    stage(0);

    for (int jt = 0; jt < nIt; ++jt) {
      __syncthreads();
      if (jt + 1 < nIt) stage(jt + 1);

      const int kvb = jt * 64;
      if (kvb > qg0 + 31) continue;
      const int buf = jt & 1;

      f32x4 s[2][4];
#pragma unroll
      for (int n = 0; n < 4; ++n) {
        const int koff = (n * 16 + l16) * 32 + (quad ^ rkey) * 8;
        bf16x8 kb0 = *(const bf16x8*)&Ks[buf][0][koff];
        bf16x8 kb1 = *(const bf16x8*)&Ks[buf][1][koff];
#pragma unroll
        for (int f = 0; f < 2; ++f) {
          f32x4 z = (f32x4){0.f, 0.f, 0.f, 0.f};
          z = __builtin_amdgcn_mfma_f32_16x16x32_bf16(kb0, qa[f][0], z, 0, 0, 0);
          z = __builtin_amdgcn_mfma_f32_16x16x32_bf16(kb1, qa[f][1], z, 0, 0, 0);
          s[f][n] = z;
        }
      }

      bf16x4 p[2][4];
      if (kvb + 63 <= qg0) {
#pragma unroll
        for (int f = 0; f < 2; ++f)
#pragma unroll
          for (int n = 0; n < 4; ++n) {
            float pe[4];
#pragma unroll
            for (int r = 0; r < 4; ++r) {
              pe[r] = fast_exp2(s[f][n][r]);
              rs[f] += pe[r];
            }
            p[f][n] = (bf16x4){(__bf16)pe[0], (__bf16)pe[1], (__bf16)pe[2], (__bf16)pe[3]};
          }
      } else {
#pragma unroll
        for (int f = 0; f < 2; ++f) {
          const int qg = qg0 + f * 16 + l16;
#pragma unroll
          for (int n = 0; n < 4; ++n) {
            const int kg0 = kvb + n * 16 + quad * 4;
            float pe[4];
#pragma unroll
            for (int r = 0; r < 4; ++r) {
              float e = fast_exp2(s[f][n][r]);
              pe[r] = (kg0 + r > qg) ? 0.f : e;
              rs[f] += pe[r];
            }
            p[f][n] = (bf16x4){(__bf16)pe[0], (__bf16)pe[1], (__bf16)pe[2], (__bf16)pe[3]};
          }
        }
      }

#pragma unroll
      for (int m = 0; m < 4; ++m) {
        const int vrow = (m * 16 + l16) * 32;
#pragma unroll
        for (int n = 0; n < 4; ++n) {
          const int clog = (n & 1) * 2 + (quad >> 1);
          const int voff = vrow + (clog ^ rkey) * 8 + (quad & 1) * 4;
          bf16x4 va = *(const bf16x4*)&Vs[buf][n >> 1][voff];
#pragma unroll
          for (int f = 0; f < 2; ++f) o[f][m] = mfma16(va, p[f][n], o[f][m]);
        }
      }
    }

#pragma unroll
    for (int f = 0; f < 2; ++f) {
      float t = rs[f];
      t += __shfl_xor(t, 16, 64);
      t += __shfl_xor(t, 32, 64);
      const float il = 1.f / t;
      const int q = qg0 + f * 16 + l16;
      ushort* dst = Ob + ((size_t)b * 2048 + q) * 1024 + h * 64;
#pragma unroll
      for (int m = 0; m < 4; ++m) {
        ushort4 w;
        w.x = f2bf(o[f][m][0] * il);
        w.y = f2bf(o[f][m][1] * il);
        w.z = f2bf(o[f][m][2] * il);
        w.w = f2bf(o[f][m][3] * il);
        *(ushort4*)(dst + m * 16 + quad * 4) = w;
      }
    }
  };

  process(15 - pair);
  __syncthreads();
  process(pair);
}

// ---------------- launch ----------------
extern "C" void kernel_launch(void* const* d_in, const int* in_sizes, int n_in,
                              void* d_out, int out_size, void* d_ws, size_t ws_size,
                              hipStream_t stream) {
  const float* x    = (const float*)d_in[0];  // [4,2048,1024]
  const float* Wqkv = (const float*)d_in[1];  // [1024,3072]
  const float* bqkv = (const float*)d_in[2];  // [3072]
  const float* Wo   = (const float*)d_in[3];  // [1024,1024]
  const float* bo   = (const float*)d_in[4];  // [1024]
  float* out = (float*)d_out;                 // [4,2048,1024] fp32

  char* ws = (char*)d_ws;
  size_t off = 0;
  auto alloc = [&](size_t bytes) {
    void* p = ws + off;
    off += (bytes + 255) & ~(size_t)255;
    return p;
  };
  ushort* xbf    = (ushort*)alloc((size_t)8192 * 1024 * 2);
  ushort* Wqkv_t = (ushort*)alloc((size_t)3072 * 1024 * 2);
  ushort* Wo_t   = (ushort*)alloc((size_t)1024 * 1024 * 2);
  ushort* Qb     = (ushort*)alloc((size_t)64 * 2048 * 64 * 2);
  ushort* Kb     = (ushort*)alloc((size_t)64 * 2048 * 64 * 2);
  ushort* Vb     = (ushort*)alloc((size_t)64 * 2048 * 64 * 2);  // tiled V^T
  ushort* Ab     = (ushort*)alloc((size_t)8192 * 1024 * 2);

  // 1. x -> bf16
  conv_bf16<<<dim3(8192), dim3(256), 0, stream>>>((const float4*)x, (ushort4*)xbf,
                                                  8192 * 1024 / 4);
  // 2. transpose weights -> bf16 [N][K]
  transpose_f32_bf16<<<dim3(96, 32), dim3(32, 8), 0, stream>>>(Wqkv, Wqkv_t, 1024, 3072);
  transpose_f32_bf16<<<dim3(32, 32), dim3(32, 8), 0, stream>>>(Wo, Wo_t, 1024, 1024);
  // 3. QKV projection, 8-phase 256^2 kernel, scatter to Q/K/Vt layouts
  gemm8_qkv<<<dim3(12, 32), dim3(512), 0, stream>>>(xbf, Wqkv_t, bqkv, Qb, Kb, Vb);
  // 4. causal flash attention (paired q-tiles: 512 uniform blocks)
  attn_fused<<<dim3(8, 64), dim3(256), 0, stream>>>(Qb, Kb, Vb, Ab);
  // 5. output projection
  gemm_bt<1><<<dim3(8, 64), dim3(256), 0, stream>>>(Ab, Wo_t, bo, nullptr, nullptr, nullptr,
                                                    out, 8192, 1024, 1024);
}